// Round 10
// baseline (1670.051 us; speedup 1.0000x reference)
//
#include <hip/hip_runtime.h>
#include <hip/hip_bf16.h>

#define DD 300        // EMB
#define C4 75         // DD/4 4-element chunks per row
#define AGS 320       // agg row stride (fp16), multiple of BK=64
#define HS 320        // h row stride (fp16), 640 B = 5 full cache lines
#define BN_EPS 1e-5f

typedef _Float16 f16x8 __attribute__((ext_vector_type(8)));   // 8 fp16 in 4 VGPRs
typedef float f32x4 __attribute__((ext_vector_type(4)));

union PackH4 { _Float16 h[4]; uint2 u; };

// async global->LDS, 16 B per lane, dest = wave-uniform base + lane*16
__device__ __forceinline__ void gld_lds16(const void* g, void* lds) {
    __builtin_amdgcn_global_load_lds(
        (const __attribute__((address_space(1))) void*)g,
        (__attribute__((address_space(3))) void*)lds, 16, 0, 0);
}

// ---------- h0 = x_emb1[x[:,0]] + x_emb2[x[:,1]]  (fp16 h, stride HS) ----------
__global__ __launch_bounds__(256) void embed_kernel(
    const int* __restrict__ x, const float* __restrict__ emb1,
    const float* __restrict__ emb2, _Float16* __restrict__ h, int total4)
{
    int i = blockIdx.x * 256 + threadIdx.x;
    if (i >= total4) return;
    int node = i / C4, chunk = i - node * C4;
    int a = x[2 * node], b = x[2 * node + 1];
    int c = chunk << 2;
    float4 v1 = *(const float4*)(emb1 + (size_t)a * DD + c);
    float4 v2 = *(const float4*)(emb2 + (size_t)b * DD + c);
    PackH4 p;
    p.h[0] = (_Float16)(v1.x + v2.x);
    p.h[1] = (_Float16)(v1.y + v2.y);
    p.h[2] = (_Float16)(v1.z + v2.z);
    p.h[3] = (_Float16)(v1.w + v2.w);
    *(uint2*)(h + (size_t)node * HS + c) = p.u;
}

// ---------- combined edge-embedding table: ec[l][a0*3+a1][c] ----------
__global__ __launch_bounds__(256) void build_ec_kernel(
    const float* __restrict__ e1, const float* __restrict__ e2, float* __restrict__ ec)
{
    int gid = blockIdx.x * 256 + threadIdx.x;
    if (gid >= 5 * 18 * DD) return;
    int l = gid / (18 * DD);
    int rem = gid - l * 18 * DD;
    int combo = rem / DD;
    int c = rem - combo * DD;
    int a0 = combo / 3, a1 = combo - a0 * 3;
    ec[gid] = e1[(size_t)l * 6 * DD + a0 * DD + c] + e2[(size_t)l * 3 * DD + a1 * DD + c];
}

// ================= CSR build =================
__global__ __launch_bounds__(256) void deg_kernel(
    const int* __restrict__ ei, int* __restrict__ deg, int E)
{
    int e = blockIdx.x * 256 + threadIdx.x;
    if (e >= E) return;
    atomicAdd(&deg[ei[E + e]], 1);
}

// block scans 1024 elements (4/thread); writes local-exclusive prefix + block total
__global__ __launch_bounds__(256) void scan1_kernel(
    const int* __restrict__ deg, int* __restrict__ pre, int* __restrict__ blockSum, int n)
{
    __shared__ int sa[256], sb[256];
    int t = threadIdx.x;
    int base = blockIdx.x * 1024 + t * 4;
    int v0 = (base + 0 < n) ? deg[base + 0] : 0;
    int v1 = (base + 1 < n) ? deg[base + 1] : 0;
    int v2 = (base + 2 < n) ? deg[base + 2] : 0;
    int v3 = (base + 3 < n) ? deg[base + 3] : 0;
    int tot = v0 + v1 + v2 + v3;
    sa[t] = tot;
    __syncthreads();
    int* src = sa; int* dst = sb;
    for (int off = 1; off < 256; off <<= 1) {
        int v = src[t];
        if (t >= off) v += src[t - off];
        dst[t] = v;
        __syncthreads();
        int* tmp = src; src = dst; dst = tmp;
    }
    int incl = src[t];
    int excl = incl - tot;
    if (base + 0 < n) pre[base + 0] = excl;
    if (base + 1 < n) pre[base + 1] = excl + v0;
    if (base + 2 < n) pre[base + 2] = excl + v0 + v1;
    if (base + 3 < n) pre[base + 3] = excl + v0 + v1 + v2;
    if (t == 255) blockSum[blockIdx.x] = incl;
}

// single-block exclusive scan of blockSum (nb <= 256)
__global__ __launch_bounds__(256) void scan2_kernel(int* __restrict__ blockSum, int nb)
{
    __shared__ int sa[256], sb[256];
    int t = threadIdx.x;
    int v = (t < nb) ? blockSum[t] : 0;
    sa[t] = v;
    __syncthreads();
    int* src = sa; int* dst = sb;
    for (int off = 1; off < 256; off <<= 1) {
        int x = src[t];
        if (t >= off) x += src[t - off];
        dst[t] = x;
        __syncthreads();
        int* tmp = src; src = dst; dst = tmp;
    }
    if (t < nb) blockSum[t] = src[t] - v;   // exclusive
}

// rowPtr[idx] = pre[idx] + blockSum[idx/1024]; rowPtr[n] = E; cursor = rowPtr
__global__ __launch_bounds__(256) void scan3_kernel(
    const int* __restrict__ pre, const int* __restrict__ blockSum,
    int* __restrict__ rowPtr, int* __restrict__ cursor, int n, int E)
{
    int idx = blockIdx.x * 256 + threadIdx.x;
    if (idx > n) return;
    int v = (idx < n) ? pre[idx] + blockSum[idx >> 10] : E;
    rowPtr[idx] = v;
    if (idx < n) cursor[idx] = v;
}

__global__ __launch_bounds__(256) void fill_kernel(
    const int* __restrict__ ei, const int* __restrict__ ea,
    int* __restrict__ cursor, int* __restrict__ edges, int E)
{
    int e = blockIdx.x * 256 + threadIdx.x;
    if (e >= E) return;
    int src = ei[e];
    int dst = ei[E + e];
    int combo = ea[2 * e] * 3 + ea[2 * e + 1];
    int slot = atomicAdd(&cursor[dst], 1);
    edges[slot] = src | (combo << 18);
}

// ---------- gather (CSR): agg[i] = self + sum_e affine(h[src]) + ec[combo] ----------
// h fp16 (stride HS). Edge loop 4-wide unrolled (named regs, rule#20-safe) so 4
// independent L3-random h-loads are in flight instead of 1 (serial-dep latency).
__global__ __launch_bounds__(256) void gather_kernel(
    const _Float16* __restrict__ h, const int* __restrict__ rowPtr,
    const int* __restrict__ edges, const float* __restrict__ ec,
    const float* __restrict__ scale, const float* __restrict__ shift, int use_affine,
    _Float16* __restrict__ agg, int n)
{
    int gid = blockIdx.x * 256 + threadIdx.x;
    int node = gid / C4, ch = gid - node * C4;
    if (node >= n) return;
    int c = ch << 2;
    float4 sc, sh;
    if (use_affine) {
        sc = *(const float4*)(scale + c);
        sh = *(const float4*)(shift + c);
    }
    PackH4 ps; ps.u = *(const uint2*)(h + (size_t)node * HS + c);  // self-loop
    float a0 = (float)ps.h[0], a1 = (float)ps.h[1], a2 = (float)ps.h[2], a3 = (float)ps.h[3];
    if (use_affine) {
        a0 = fmaxf(fmaf(sc.x, a0, sh.x), 0.f);
        a1 = fmaxf(fmaf(sc.y, a1, sh.y), 0.f);
        a2 = fmaxf(fmaf(sc.z, a2, sh.z), 0.f);
        a3 = fmaxf(fmaf(sc.w, a3, sh.w), 0.f);
    }
    float4 es = *(const float4*)(ec + 12 * DD + c);   // self-loop combo 12
    a0 += es.x; a1 += es.y; a2 += es.z; a3 += es.w;

    int e = rowPtr[node];
    const int end = rowPtr[node + 1];

    // 4-wide pipeline: all 4 h-loads issued before any accumulation
    for (; e + 3 < end; e += 4) {
        int pk0 = edges[e + 0], pk1 = edges[e + 1];
        int pk2 = edges[e + 2], pk3 = edges[e + 3];
        PackH4 q0, q1, q2, q3;
        q0.u = *(const uint2*)(h + (size_t)(pk0 & 0x3FFFF) * HS + c);
        q1.u = *(const uint2*)(h + (size_t)(pk1 & 0x3FFFF) * HS + c);
        q2.u = *(const uint2*)(h + (size_t)(pk2 & 0x3FFFF) * HS + c);
        q3.u = *(const uint2*)(h + (size_t)(pk3 & 0x3FFFF) * HS + c);
        float4 e0 = *(const float4*)(ec + (pk0 >> 18) * DD + c);
        float4 e1 = *(const float4*)(ec + (pk1 >> 18) * DD + c);
        float4 e2 = *(const float4*)(ec + (pk2 >> 18) * DD + c);
        float4 e3 = *(const float4*)(ec + (pk3 >> 18) * DD + c);
        float h00 = (float)q0.h[0], h01 = (float)q0.h[1], h02 = (float)q0.h[2], h03 = (float)q0.h[3];
        float h10 = (float)q1.h[0], h11 = (float)q1.h[1], h12 = (float)q1.h[2], h13 = (float)q1.h[3];
        float h20 = (float)q2.h[0], h21 = (float)q2.h[1], h22 = (float)q2.h[2], h23 = (float)q2.h[3];
        float h30 = (float)q3.h[0], h31 = (float)q3.h[1], h32 = (float)q3.h[2], h33 = (float)q3.h[3];
        if (use_affine) {
            h00 = fmaxf(fmaf(sc.x, h00, sh.x), 0.f); h01 = fmaxf(fmaf(sc.y, h01, sh.y), 0.f);
            h02 = fmaxf(fmaf(sc.z, h02, sh.z), 0.f); h03 = fmaxf(fmaf(sc.w, h03, sh.w), 0.f);
            h10 = fmaxf(fmaf(sc.x, h10, sh.x), 0.f); h11 = fmaxf(fmaf(sc.y, h11, sh.y), 0.f);
            h12 = fmaxf(fmaf(sc.z, h12, sh.z), 0.f); h13 = fmaxf(fmaf(sc.w, h13, sh.w), 0.f);
            h20 = fmaxf(fmaf(sc.x, h20, sh.x), 0.f); h21 = fmaxf(fmaf(sc.y, h21, sh.y), 0.f);
            h22 = fmaxf(fmaf(sc.z, h22, sh.z), 0.f); h23 = fmaxf(fmaf(sc.w, h23, sh.w), 0.f);
            h30 = fmaxf(fmaf(sc.x, h30, sh.x), 0.f); h31 = fmaxf(fmaf(sc.y, h31, sh.y), 0.f);
            h32 = fmaxf(fmaf(sc.z, h32, sh.z), 0.f); h33 = fmaxf(fmaf(sc.w, h33, sh.w), 0.f);
        }
        a0 += (h00 + e0.x) + (h10 + e1.x) + (h20 + e2.x) + (h30 + e3.x);
        a1 += (h01 + e0.y) + (h11 + e1.y) + (h21 + e2.y) + (h31 + e3.y);
        a2 += (h02 + e0.z) + (h12 + e1.z) + (h22 + e2.z) + (h32 + e3.z);
        a3 += (h03 + e0.w) + (h13 + e1.w) + (h23 + e2.w) + (h33 + e3.w);
    }
    for (; e < end; ++e) {
        int pk = edges[e];
        PackH4 ph; ph.u = *(const uint2*)(h + (size_t)(pk & 0x3FFFF) * HS + c);
        float h0 = (float)ph.h[0], h1 = (float)ph.h[1], h2 = (float)ph.h[2], h3 = (float)ph.h[3];
        if (use_affine) {
            h0 = fmaxf(fmaf(sc.x, h0, sh.x), 0.f);
            h1 = fmaxf(fmaf(sc.y, h1, sh.y), 0.f);
            h2 = fmaxf(fmaf(sc.z, h2, sh.z), 0.f);
            h3 = fmaxf(fmaf(sc.w, h3, sh.w), 0.f);
        }
        float4 ev = *(const float4*)(ec + (pk >> 18) * DD + c);
        a0 += h0 + ev.x;
        a1 += h1 + ev.y;
        a2 += h2 + ev.z;
        a3 += h3 + ev.w;
    }
    PackH4 p;
    p.h[0] = (_Float16)a0;
    p.h[1] = (_Float16)a1;
    p.h[2] = (_Float16)a2;
    p.h[3] = (_Float16)a3;
    *(uint2*)(agg + (size_t)node * AGS + c) = p.u;
}

// ---------- convert fp32 weights (out,in) -> padded fp16 ----------
__global__ __launch_bounds__(256) void convert_w_kernel(
    const float* __restrict__ w, _Float16* __restrict__ wf,
    int rows, int cols, int rowsP, int colsP)
{
    int gid = blockIdx.x * 256 + threadIdx.x;
    int total = 5 * rowsP * colsP;
    if (gid >= total) return;
    int l = gid / (rowsP * colsP);
    int rem = gid - l * (rowsP * colsP);
    int r = rem / colsP;
    int k = rem - r * colsP;
    float v = (r < rows && k < cols) ? w[((size_t)l * rows + r) * cols + k] : 0.f;
    wf[gid] = (_Float16)v;
}

// ---------- LDS-staged fp16 MFMA GEMM, 64x128 tile (r3/r9 structure) ----------
// C = act(A @ W^T + bias) -> fp16 out (stride outStride, zero pads); optional BN stats.
// launch_bounds(256,6): perf has tracked occupancy monotonically across 8 GEMM
// variants (19.5%->161us ... 44%->113us); min-waves 4->6 forces the allocator
// under 85 VGPR (fits: ~44 addr + 32 acc) so 6 blocks/CU (24KB LDS each) are eligible.
template <bool RELU, bool DO_STATS>
__global__ __launch_bounds__(256, 6) void mfma_gemm_lds(
    const _Float16* __restrict__ A, const _Float16* __restrict__ W,
    const float* __restrict__ bias, _Float16* __restrict__ out,
    float* __restrict__ sum, float* __restrict__ sumsq,
    int M, int Kp, int outStride, int outN, int nCol)
{
    __shared__ __attribute__((aligned(16))) unsigned short sA[64 * 64];
    __shared__ __attribute__((aligned(16))) unsigned short sB[128 * 64];

    const int bid = blockIdx.x;
    const int group = bid / (8 * nCol);
    const int within = bid - group * 8 * nCol;
    const int rowT = group * 8 + (within & 7);
    const int colT = within >> 3;
    const int bm = rowT << 6;                        // 64-row tiles
    const int bn = colT << 7;                        // 128-col tiles

    const int tid = threadIdx.x;
    const int lane = tid & 63, wv = tid >> 6;
    const int wy = wv & 1, wx = wv >> 1;            // 2x2 wave grid: 32-row x 64-col
    const int quad = lane >> 4, l16 = lane & 15;

    const int r8 = lane >> 3;                        // staging row within call
    const int chv = (lane & 7) ^ r8;                 // swizzled chunk to fetch

    f32x4 acc[2][4] = {};

    for (int k0 = 0; k0 < Kp; k0 += 64) {
        __syncthreads();
        // A: 64 rows; each wave stages 16 rows (2 calls)
#pragma unroll
        for (int j = 0; j < 2; ++j) {
            int rloc = wv * 16 + j * 8 + r8;
            gld_lds16(A + (size_t)(bm + rloc) * Kp + k0 + chv * 8,
                      &sA[(wv * 16 + j * 8) * 64]);
        }
        // B: 128 rows; each wave stages 32 rows (4 calls)
#pragma unroll
        for (int j = 0; j < 4; ++j) {
            int rloc = wv * 32 + j * 8 + r8;
            gld_lds16(W + (size_t)(bn + rloc) * Kp + k0 + chv * 8,
                      &sB[(wv * 32 + j * 8) * 64]);
        }
        __syncthreads();
#pragma unroll
        for (int kk = 0; kk < 2; ++kk) {
            f16x8 a[2], b[4];
#pragma unroll
            for (int i = 0; i < 2; ++i) {
                int rA = wy * 32 + i * 16 + l16;
                int slotA = (kk * 4 + quad) ^ (rA & 7);
                a[i] = *(const f16x8*)&sA[rA * 64 + slotA * 8];
            }
#pragma unroll
            for (int j = 0; j < 4; ++j) {
                int rB = wx * 64 + j * 16 + l16;
                int slotB = (kk * 4 + quad) ^ (rB & 7);
                b[j] = *(const f16x8*)&sB[rB * 64 + slotB * 8];
            }
#pragma unroll
            for (int i = 0; i < 2; ++i)
#pragma unroll
                for (int j = 0; j < 4; ++j)
                    acc[i][j] = __builtin_amdgcn_mfma_f32_16x16x32_f16(
                        a[i], b[j], acc[i][j], 0, 0, 0);
        }
    }

    // epilogue: C/D layout col=lane&15, row=quad*4+reg  [m89-verified]
#pragma unroll
    for (int j = 0; j < 4; ++j) {
        int col = bn + wx * 64 + j * 16 + l16;
        float bv = (col < outN) ? bias[col] : 0.f;
        float cs = 0.f, cq = 0.f;   // per-lane column partial (rows of this wave)
#pragma unroll
        for (int i = 0; i < 2; ++i) {
            int rowBase = bm + wy * 32 + i * 16 + (quad << 2);
#pragma unroll
            for (int r = 0; r < 4; ++r) {
                int row = rowBase + r;
                if (row >= M) continue;
                float v = acc[i][j][r] + bv;
                if constexpr (DO_STATS) { if (col < outN) { cs += v; cq += v * v; } }
                float o;
                if constexpr (RELU) o = (col < outN) ? fmaxf(v, 0.f) : 0.f;
                else                o = (col < outN) ? v : 0.f;      // zero pads
                if (col < outStride)
                    out[(size_t)row * outStride + col] = (_Float16)o;
            }
        }
        if constexpr (DO_STATS) {
            // reduce across quads: lanes l, l+16, l+32, l+48 hold same column
            cs += __shfl_down(cs, 32); cq += __shfl_down(cq, 32);
            cs += __shfl_down(cs, 16); cq += __shfl_down(cq, 16);
            if (quad == 0 && col < outN) {
                atomicAdd(&sum[col], cs);
                atomicAdd(&sumsq[col], cq);
            }
        }
    }
}

__global__ void finalize_kernel(
    const float* __restrict__ sum, const float* __restrict__ sumsq,
    const float* __restrict__ gamma, const float* __restrict__ beta,
    float* __restrict__ scale, float* __restrict__ shift, float inv_n)
{
    int c = threadIdx.x;
    if (c < DD) {
        float mu = sum[c] * inv_n;
        float var = sumsq[c] * inv_n - mu * mu;
        float inv = rsqrtf(var + BN_EPS);
        float sc = gamma[c] * inv;
        scale[c] = sc;
        shift[c] = fmaf(-mu, sc, beta[c]);
    }
}

// ---------- final: out = scale*h + shift (fp16 h strided -> fp32 out compact) ----------
__global__ __launch_bounds__(256) void apply_kernel(
    const _Float16* __restrict__ h, const float* __restrict__ scale,
    const float* __restrict__ shift, float* __restrict__ out, int total4)
{
    int i = blockIdx.x * 256 + threadIdx.x;
    if (i >= total4) return;
    int node = i / C4;
    int c = (i - node * C4) << 2;
    PackH4 ph; ph.u = *(const uint2*)(h + (size_t)node * HS + c);
    float4 r;
    r.x = fmaf(scale[c + 0], (float)ph.h[0], shift[c + 0]);
    r.y = fmaf(scale[c + 1], (float)ph.h[1], shift[c + 1]);
    r.z = fmaf(scale[c + 2], (float)ph.h[2], shift[c + 2]);
    r.w = fmaf(scale[c + 3], (float)ph.h[3], shift[c + 3]);
    ((float4*)out)[i] = r;
}

extern "C" void kernel_launch(void* const* d_in, const int* in_sizes, int n_in,
                              void* d_out, int out_size, void* d_ws, size_t ws_size,
                              hipStream_t stream)
{
    const int*   x      = (const int*)d_in[0];
    const int*   ei     = (const int*)d_in[1];
    const int*   ea     = (const int*)d_in[2];
    const float* x_emb1 = (const float*)d_in[3];
    const float* x_emb2 = (const float*)d_in[4];
    const float* e_emb1 = (const float*)d_in[5];
    const float* e_emb2 = (const float*)d_in[6];
    const float* w1     = (const float*)d_in[7];
    const float* b1     = (const float*)d_in[8];
    const float* w2     = (const float*)d_in[9];
    const float* b2     = (const float*)d_in[10];
    const float* gamma  = (const float*)d_in[11];
    const float* beta   = (const float*)d_in[12];

    const int n = in_sizes[0] / 2;           // 100000
    const int E = in_sizes[1] / 2;           // 250000
    const int nRowT = (n + 63) / 64;         // 1563 row tiles (64 rows each)
    const int nRowTP = ((nRowT + 7) / 8) * 8;     // 1568 (multiple of 8 for swizzle)
    const int MpA = nRowTP * 64;             // 100352 padded rows
    const int Kp1 = AGS, Kp2 = 640;          // padded K (multiples of BK=64)
    const int NP1 = 640, NP2 = 384;          // padded output dims (tiles of 128)

    // ---- workspace layout ----
    char* p = (char*)d_ws;
    auto alloc = [&](size_t bytes) -> void* {
        void* r = (void*)p;
        p += (bytes + 255) & ~(size_t)255;
        return r;
    };
    _Float16* agg  = (_Float16*)alloc((size_t)MpA * Kp1 * 2);
    _Float16* hid  = (_Float16*)alloc((size_t)MpA * Kp2 * 2);
    _Float16* h    = (_Float16*)alloc((size_t)n * HS * 2);   // fp16 h, 640B rows
    _Float16* w1f  = (_Float16*)alloc((size_t)5 * NP1 * Kp1 * 2);
    _Float16* w2f  = (_Float16*)alloc((size_t)5 * NP2 * Kp2 * 2);
    float* ec     = (float*)alloc((size_t)5 * 18 * DD * 4);
    int*   deg    = (int*)alloc((size_t)n * 4);
    int*   rowPtr = (int*)alloc((size_t)(n + 1) * 4);
    int*   cursor = (int*)alloc((size_t)n * 4);
    int*   blockSum = (int*)alloc(256 * 4);
    int*   edges  = (int*)alloc((size_t)E * 4);
    float* sum   = (float*)alloc(320 * 4);
    float* sumsq = (float*)alloc(320 * 4);
    float* scale = (float*)alloc(320 * 4);
    float* shift = (float*)alloc(320 * 4);

    const int total4 = n * C4;
    const int nb = (n + 1023) / 1024;    // scan blocks (98)

    // ---- one-time (per call) prep ----
    {
        convert_w_kernel<<<(5 * NP1 * Kp1 + 255) / 256, 256, 0, stream>>>(w1, w1f, 600, 300, NP1, Kp1);
        convert_w_kernel<<<(5 * NP2 * Kp2 + 255) / 256, 256, 0, stream>>>(w2, w2f, 300, 600, NP2, Kp2);
        build_ec_kernel<<<(5 * 18 * DD + 255) / 256, 256, 0, stream>>>(e_emb1, e_emb2, ec);
        // CSR build
        hipMemsetAsync(deg, 0, (size_t)n * 4, stream);
        deg_kernel<<<(E + 255) / 256, 256, 0, stream>>>(ei, deg, E);
        scan1_kernel<<<nb, 256, 0, stream>>>(deg, cursor /*reuse as pre*/, blockSum, n);
        scan2_kernel<<<1, 256, 0, stream>>>(blockSum, nb);
        scan3_kernel<<<(n + 256) / 256, 256, 0, stream>>>(cursor, blockSum, rowPtr, deg /*reuse as cursor*/, n, E);
        fill_kernel<<<(E + 255) / 256, 256, 0, stream>>>(ei, ea, deg, edges, E);
        // agg zeroed once: k-pads + tail rows stay 0 across all layers
        hipMemsetAsync(agg, 0, (size_t)MpA * Kp1 * 2, stream);
        embed_kernel<<<(total4 + 255) / 256, 256, 0, stream>>>(x, x_emb1, x_emb2, h, total4);
    }

    const int gatherTotal = n * C4;
    const int nCol1 = NP1 / 128;   // 5
    const int nCol2 = NP2 / 128;   // 3
    const int g1 = nRowTP * nCol1; // 7840 blocks
    const int g2 = nRowTP * nCol2; // 4704 blocks

    for (int l = 0; l < 5; l++) {
        hipMemsetAsync(sum, 0, 2 * 320 * sizeof(float), stream);  // sum+sumsq contiguous
        gather_kernel<<<(gatherTotal + 255) / 256, 256, 0, stream>>>(
            h, rowPtr, edges, ec + (size_t)l * 18 * DD, scale, shift, l > 0 ? 1 : 0,
            agg, n);
        // GEMM1: agg[Mp,320] x w1[640,320] -> hid fp16 (relu, stride 640)
        mfma_gemm_lds<true, false><<<g1, 256, 0, stream>>>(
            agg, w1f + (size_t)l * NP1 * Kp1,
            b1 + (size_t)l * 600, hid, nullptr, nullptr,
            n, Kp1, Kp2, 600, nCol1);
        // GEMM2: hid[Mp,640] x w2[384,640] -> h fp16 (stride HS, no relu) + BN stats
        mfma_gemm_lds<false, true><<<g2, 256, 0, stream>>>(
            hid, w2f + (size_t)l * NP2 * Kp2,
            b2 + (size_t)l * 300, h, sum, sumsq,
            n, Kp2, HS, 300, nCol2);
        finalize_kernel<<<1, 320, 0, stream>>>(sum, sumsq, gamma + (size_t)l * DD,
                                               beta + (size_t)l * DD, scale, shift,
                                               1.0f / (float)n);
    }
    apply_kernel<<<(total4 + 255) / 256, 256, 0, stream>>>(h, scale, shift,
                                                           (float*)d_out, total4);
}

// Round 11
// 1558.212 us; speedup vs baseline: 1.0718x; 1.0718x over previous
//
#include <hip/hip_runtime.h>
#include <hip/hip_bf16.h>

#define DD 300        // EMB
#define C4 75         // DD/4 4-element chunks per row
#define CG 40         // 16B chunks per h/agg row (HS/8)
#define AGS 320       // agg row stride (fp16), multiple of BK=64
#define HS 320        // h row stride (fp16), 640 B = 5 full cache lines
#define ECS 320       // ec row stride (fp32), zero-padded cols 300..319
#define BN_EPS 1e-5f

typedef _Float16 f16x8 __attribute__((ext_vector_type(8)));   // 8 fp16 in 4 VGPRs
typedef float f32x4 __attribute__((ext_vector_type(4)));

union PackH4 { _Float16 h[4]; uint2 u; };

// async global->LDS, 16 B per lane, dest = wave-uniform base + lane*16
__device__ __forceinline__ void gld_lds16(const void* g, void* lds) {
    __builtin_amdgcn_global_load_lds(
        (const __attribute__((address_space(1))) void*)g,
        (__attribute__((address_space(3))) void*)lds, 16, 0, 0);
}

// ---------- h0 = x_emb1[x[:,0]] + x_emb2[x[:,1]]  (fp16 h, stride HS) ----------
// h pre-zeroed once in prep => pad cols 300..319 stay 0
__global__ __launch_bounds__(256) void embed_kernel(
    const int* __restrict__ x, const float* __restrict__ emb1,
    const float* __restrict__ emb2, _Float16* __restrict__ h, int total4)
{
    int i = blockIdx.x * 256 + threadIdx.x;
    if (i >= total4) return;
    int node = i / C4, chunk = i - node * C4;
    int a = x[2 * node], b = x[2 * node + 1];
    int c = chunk << 2;
    float4 v1 = *(const float4*)(emb1 + (size_t)a * DD + c);
    float4 v2 = *(const float4*)(emb2 + (size_t)b * DD + c);
    PackH4 p;
    p.h[0] = (_Float16)(v1.x + v2.x);
    p.h[1] = (_Float16)(v1.y + v2.y);
    p.h[2] = (_Float16)(v1.z + v2.z);
    p.h[3] = (_Float16)(v1.w + v2.w);
    *(uint2*)(h + (size_t)node * HS + c) = p.u;
}

// ---------- combined edge-embedding table: ec[l][a0*3+a1][c], stride ECS ----------
__global__ __launch_bounds__(256) void build_ec_kernel(
    const float* __restrict__ e1, const float* __restrict__ e2, float* __restrict__ ec)
{
    int gid = blockIdx.x * 256 + threadIdx.x;
    if (gid >= 5 * 18 * ECS) return;
    int l = gid / (18 * ECS);
    int rem = gid - l * 18 * ECS;
    int combo = rem / ECS;
    int c = rem - combo * ECS;
    int a0 = combo / 3, a1 = combo - a0 * 3;
    float v = 0.f;
    if (c < DD)
        v = e1[(size_t)l * 6 * DD + a0 * DD + c] + e2[(size_t)l * 3 * DD + a1 * DD + c];
    ec[gid] = v;     // zero pads for c >= 300
}

// ================= CSR build =================
__global__ __launch_bounds__(256) void deg_kernel(
    const int* __restrict__ ei, int* __restrict__ deg, int E)
{
    int e = blockIdx.x * 256 + threadIdx.x;
    if (e >= E) return;
    atomicAdd(&deg[ei[E + e]], 1);
}

// block scans 1024 elements (4/thread); writes local-exclusive prefix + block total
__global__ __launch_bounds__(256) void scan1_kernel(
    const int* __restrict__ deg, int* __restrict__ pre, int* __restrict__ blockSum, int n)
{
    __shared__ int sa[256], sb[256];
    int t = threadIdx.x;
    int base = blockIdx.x * 1024 + t * 4;
    int v0 = (base + 0 < n) ? deg[base + 0] : 0;
    int v1 = (base + 1 < n) ? deg[base + 1] : 0;
    int v2 = (base + 2 < n) ? deg[base + 2] : 0;
    int v3 = (base + 3 < n) ? deg[base + 3] : 0;
    int tot = v0 + v1 + v2 + v3;
    sa[t] = tot;
    __syncthreads();
    int* src = sa; int* dst = sb;
    for (int off = 1; off < 256; off <<= 1) {
        int v = src[t];
        if (t >= off) v += src[t - off];
        dst[t] = v;
        __syncthreads();
        int* tmp = src; src = dst; dst = tmp;
    }
    int incl = src[t];
    int excl = incl - tot;
    if (base + 0 < n) pre[base + 0] = excl;
    if (base + 1 < n) pre[base + 1] = excl + v0;
    if (base + 2 < n) pre[base + 2] = excl + v0 + v1;
    if (base + 3 < n) pre[base + 3] = excl + v0 + v1 + v2;
    if (t == 255) blockSum[blockIdx.x] = incl;
}

// single-block exclusive scan of blockSum (nb <= 256)
__global__ __launch_bounds__(256) void scan2_kernel(int* __restrict__ blockSum, int nb)
{
    __shared__ int sa[256], sb[256];
    int t = threadIdx.x;
    int v = (t < nb) ? blockSum[t] : 0;
    sa[t] = v;
    __syncthreads();
    int* src = sa; int* dst = sb;
    for (int off = 1; off < 256; off <<= 1) {
        int x = src[t];
        if (t >= off) x += src[t - off];
        dst[t] = x;
        __syncthreads();
        int* tmp = src; src = dst; dst = tmp;
    }
    if (t < nb) blockSum[t] = src[t] - v;   // exclusive
}

// rowPtr[idx] = pre[idx] + blockSum[idx/1024]; rowPtr[n] = E; cursor = rowPtr
__global__ __launch_bounds__(256) void scan3_kernel(
    const int* __restrict__ pre, const int* __restrict__ blockSum,
    int* __restrict__ rowPtr, int* __restrict__ cursor, int n, int E)
{
    int idx = blockIdx.x * 256 + threadIdx.x;
    if (idx > n) return;
    int v = (idx < n) ? pre[idx] + blockSum[idx >> 10] : E;
    rowPtr[idx] = v;
    if (idx < n) cursor[idx] = v;
}

__global__ __launch_bounds__(256) void fill_kernel(
    const int* __restrict__ ei, const int* __restrict__ ea,
    int* __restrict__ cursor, int* __restrict__ edges, int E)
{
    int e = blockIdx.x * 256 + threadIdx.x;
    if (e >= E) return;
    int src = ei[e];
    int dst = ei[E + e];
    int combo = ea[2 * e] * 3 + ea[2 * e + 1];
    int slot = atomicAdd(&cursor[dst], 1);
    edges[slot] = src | (combo << 18);
}

// ---------- gather (CSR): agg[i] = self + sum_e affine(h[src]) + ec[combo] ----------
// 16B-chunk version: 40 threads/node (vs 75), one uint4 h-load per edge per thread.
// Pads are exact zeros end-to-end: h pads 0, ec pads 0, scale/shift pads 0 =>
// agg pads compute to 0 (and feed zero-padded W1 K-cols regardless).
__global__ __launch_bounds__(256) void gather_kernel(
    const _Float16* __restrict__ h, const int* __restrict__ rowPtr,
    const int* __restrict__ edges, const float* __restrict__ ec,
    const float* __restrict__ scale, const float* __restrict__ shift, int use_affine,
    _Float16* __restrict__ agg, int n)
{
    int gid = blockIdx.x * 256 + threadIdx.x;
    int node = gid / CG, ch = gid - node * CG;
    if (node >= n) return;
    int c = ch << 3;

    float s[8], t[8];
    if (use_affine) {
        *(float4*)&s[0] = *(const float4*)(scale + c);
        *(float4*)&s[4] = *(const float4*)(scale + c + 4);
        *(float4*)&t[0] = *(const float4*)(shift + c);
        *(float4*)&t[4] = *(const float4*)(shift + c + 4);
    }

    float a[8];
    {   // self-loop (combo 12)
        f16x8 hv = *(const f16x8*)(h + (size_t)node * HS + c);
#pragma unroll
        for (int k = 0; k < 8; ++k) {
            float v = (float)hv[k];
            if (use_affine) v = fmaxf(fmaf(s[k], v, t[k]), 0.f);
            a[k] = v;
        }
        float e0[8];
        *(float4*)&e0[0] = *(const float4*)(ec + 12 * ECS + c);
        *(float4*)&e0[4] = *(const float4*)(ec + 12 * ECS + c + 4);
#pragma unroll
        for (int k = 0; k < 8; ++k) a[k] += e0[k];
    }

    int e = rowPtr[node];
    const int end = rowPtr[node + 1];
    for (; e < end; ++e) {
        int pk = edges[e];
        int src = pk & 0x3FFFF;
        int combo = pk >> 18;
        f16x8 hv = *(const f16x8*)(h + (size_t)src * HS + c);
        float ev[8];
        *(float4*)&ev[0] = *(const float4*)(ec + combo * ECS + c);
        *(float4*)&ev[4] = *(const float4*)(ec + combo * ECS + c + 4);
#pragma unroll
        for (int k = 0; k < 8; ++k) {
            float v = (float)hv[k];
            if (use_affine) v = fmaxf(fmaf(s[k], v, t[k]), 0.f);
            a[k] += v + ev[k];
        }
    }

    f16x8 o;
#pragma unroll
    for (int k = 0; k < 8; ++k) o[k] = (_Float16)a[k];
    *(f16x8*)(agg + (size_t)node * AGS + c) = o;
}

// ---------- convert fp32 weights (out,in) -> padded fp16 ----------
__global__ __launch_bounds__(256) void convert_w_kernel(
    const float* __restrict__ w, _Float16* __restrict__ wf,
    int rows, int cols, int rowsP, int colsP)
{
    int gid = blockIdx.x * 256 + threadIdx.x;
    int total = 5 * rowsP * colsP;
    if (gid >= total) return;
    int l = gid / (rowsP * colsP);
    int rem = gid - l * (rowsP * colsP);
    int r = rem / colsP;
    int k = rem - r * colsP;
    float v = (r < rows && k < cols) ? w[((size_t)l * rows + r) * cols + k] : 0.f;
    wf[gid] = (_Float16)v;
}

// ---------- LDS-staged fp16 MFMA GEMM, 64x128 tile (r9-exact, best measured) ----------
// C = act(A @ W^T + bias) -> fp16 out (stride outStride, zero pads); optional BN stats.
// History: 8 structures {128² single/dbuf, 512t, BK128, counted-vmcnt, A-to-reg} all
// 124-174us; this config = 113us. launch_bounds(256,6) raised occ 44->51% but dur
// 113->116 => occupancy lever exhausted; (256,4) is the measured best.
template <bool RELU, bool DO_STATS>
__global__ __launch_bounds__(256, 4) void mfma_gemm_lds(
    const _Float16* __restrict__ A, const _Float16* __restrict__ W,
    const float* __restrict__ bias, _Float16* __restrict__ out,
    float* __restrict__ sum, float* __restrict__ sumsq,
    int M, int Kp, int outStride, int outN, int nCol)
{
    __shared__ __attribute__((aligned(16))) unsigned short sA[64 * 64];
    __shared__ __attribute__((aligned(16))) unsigned short sB[128 * 64];

    const int bid = blockIdx.x;
    const int group = bid / (8 * nCol);
    const int within = bid - group * 8 * nCol;
    const int rowT = group * 8 + (within & 7);
    const int colT = within >> 3;
    const int bm = rowT << 6;                        // 64-row tiles
    const int bn = colT << 7;                        // 128-col tiles

    const int tid = threadIdx.x;
    const int lane = tid & 63, wv = tid >> 6;
    const int wy = wv & 1, wx = wv >> 1;            // 2x2 wave grid: 32-row x 64-col
    const int quad = lane >> 4, l16 = lane & 15;

    const int r8 = lane >> 3;                        // staging row within call
    const int chv = (lane & 7) ^ r8;                 // swizzled chunk to fetch

    f32x4 acc[2][4] = {};

    for (int k0 = 0; k0 < Kp; k0 += 64) {
        __syncthreads();
        // A: 64 rows; each wave stages 16 rows (2 calls)
#pragma unroll
        for (int j = 0; j < 2; ++j) {
            int rloc = wv * 16 + j * 8 + r8;
            gld_lds16(A + (size_t)(bm + rloc) * Kp + k0 + chv * 8,
                      &sA[(wv * 16 + j * 8) * 64]);
        }
        // B: 128 rows; each wave stages 32 rows (4 calls)
#pragma unroll
        for (int j = 0; j < 4; ++j) {
            int rloc = wv * 32 + j * 8 + r8;
            gld_lds16(W + (size_t)(bn + rloc) * Kp + k0 + chv * 8,
                      &sB[(wv * 32 + j * 8) * 64]);
        }
        __syncthreads();
#pragma unroll
        for (int kk = 0; kk < 2; ++kk) {
            f16x8 a[2], b[4];
#pragma unroll
            for (int i = 0; i < 2; ++i) {
                int rA = wy * 32 + i * 16 + l16;
                int slotA = (kk * 4 + quad) ^ (rA & 7);
                a[i] = *(const f16x8*)&sA[rA * 64 + slotA * 8];
            }
#pragma unroll
            for (int j = 0; j < 4; ++j) {
                int rB = wx * 64 + j * 16 + l16;
                int slotB = (kk * 4 + quad) ^ (rB & 7);
                b[j] = *(const f16x8*)&sB[rB * 64 + slotB * 8];
            }
#pragma unroll
            for (int i = 0; i < 2; ++i)
#pragma unroll
                for (int j = 0; j < 4; ++j)
                    acc[i][j] = __builtin_amdgcn_mfma_f32_16x16x32_f16(
                        a[i], b[j], acc[i][j], 0, 0, 0);
        }
    }

    // epilogue: C/D layout col=lane&15, row=quad*4+reg  [m89-verified]
#pragma unroll
    for (int j = 0; j < 4; ++j) {
        int col = bn + wx * 64 + j * 16 + l16;
        float bv = (col < outN) ? bias[col] : 0.f;
        float cs = 0.f, cq = 0.f;   // per-lane column partial (rows of this wave)
#pragma unroll
        for (int i = 0; i < 2; ++i) {
            int rowBase = bm + wy * 32 + i * 16 + (quad << 2);
#pragma unroll
            for (int r = 0; r < 4; ++r) {
                int row = rowBase + r;
                if (row >= M) continue;
                float v = acc[i][j][r] + bv;
                if constexpr (DO_STATS) { if (col < outN) { cs += v; cq += v * v; } }
                float o;
                if constexpr (RELU) o = (col < outN) ? fmaxf(v, 0.f) : 0.f;
                else                o = (col < outN) ? v : 0.f;      // zero pads
                if (col < outStride)
                    out[(size_t)row * outStride + col] = (_Float16)o;
            }
        }
        if constexpr (DO_STATS) {
            // reduce across quads: lanes l, l+16, l+32, l+48 hold same column
            cs += __shfl_down(cs, 32); cq += __shfl_down(cq, 32);
            cs += __shfl_down(cs, 16); cq += __shfl_down(cq, 16);
            if (quad == 0 && col < outN) {
                atomicAdd(&sum[col], cs);
                atomicAdd(&sumsq[col], cq);
            }
        }
    }
}

__global__ void finalize_kernel(
    const float* __restrict__ sum, const float* __restrict__ sumsq,
    const float* __restrict__ gamma, const float* __restrict__ beta,
    float* __restrict__ scale, float* __restrict__ shift, float inv_n)
{
    int c = threadIdx.x;
    if (c < DD) {
        float mu = sum[c] * inv_n;
        float var = sumsq[c] * inv_n - mu * mu;
        float inv = rsqrtf(var + BN_EPS);
        float sc = gamma[c] * inv;
        scale[c] = sc;
        shift[c] = fmaf(-mu, sc, beta[c]);
    } else if (c < 320) {
        scale[c] = 0.f;   // pad chunks in gather compute exact 0
        shift[c] = 0.f;
    }
}

// ---------- final: out = scale*h + shift (fp16 h strided -> fp32 out compact) ----------
__global__ __launch_bounds__(256) void apply_kernel(
    const _Float16* __restrict__ h, const float* __restrict__ scale,
    const float* __restrict__ shift, float* __restrict__ out, int total4)
{
    int i = blockIdx.x * 256 + threadIdx.x;
    if (i >= total4) return;
    int node = i / C4;
    int c = (i - node * C4) << 2;
    PackH4 ph; ph.u = *(const uint2*)(h + (size_t)node * HS + c);
    float4 r;
    r.x = fmaf(scale[c + 0], (float)ph.h[0], shift[c + 0]);
    r.y = fmaf(scale[c + 1], (float)ph.h[1], shift[c + 1]);
    r.z = fmaf(scale[c + 2], (float)ph.h[2], shift[c + 2]);
    r.w = fmaf(scale[c + 3], (float)ph.h[3], shift[c + 3]);
    ((float4*)out)[i] = r;
}

extern "C" void kernel_launch(void* const* d_in, const int* in_sizes, int n_in,
                              void* d_out, int out_size, void* d_ws, size_t ws_size,
                              hipStream_t stream)
{
    const int*   x      = (const int*)d_in[0];
    const int*   ei     = (const int*)d_in[1];
    const int*   ea     = (const int*)d_in[2];
    const float* x_emb1 = (const float*)d_in[3];
    const float* x_emb2 = (const float*)d_in[4];
    const float* e_emb1 = (const float*)d_in[5];
    const float* e_emb2 = (const float*)d_in[6];
    const float* w1     = (const float*)d_in[7];
    const float* b1     = (const float*)d_in[8];
    const float* w2     = (const float*)d_in[9];
    const float* b2     = (const float*)d_in[10];
    const float* gamma  = (const float*)d_in[11];
    const float* beta   = (const float*)d_in[12];

    const int n = in_sizes[0] / 2;           // 100000
    const int E = in_sizes[1] / 2;           // 250000
    const int nRowT = (n + 63) / 64;         // 1563 row tiles (64 rows each)
    const int nRowTP = ((nRowT + 7) / 8) * 8;     // 1568 (multiple of 8 for swizzle)
    const int MpA = nRowTP * 64;             // 100352 padded rows
    const int Kp1 = AGS, Kp2 = 640;          // padded K (multiples of BK=64)
    const int NP1 = 640, NP2 = 384;          // padded output dims (tiles of 128)

    // ---- workspace layout ----
    char* p = (char*)d_ws;
    auto alloc = [&](size_t bytes) -> void* {
        void* r = (void*)p;
        p += (bytes + 255) & ~(size_t)255;
        return r;
    };
    _Float16* agg  = (_Float16*)alloc((size_t)MpA * Kp1 * 2);
    _Float16* hid  = (_Float16*)alloc((size_t)MpA * Kp2 * 2);
    _Float16* h    = (_Float16*)alloc((size_t)n * HS * 2);   // fp16 h, 640B rows
    _Float16* w1f  = (_Float16*)alloc((size_t)5 * NP1 * Kp1 * 2);
    _Float16* w2f  = (_Float16*)alloc((size_t)5 * NP2 * Kp2 * 2);
    float* ec     = (float*)alloc((size_t)5 * 18 * ECS * 4);
    int*   deg    = (int*)alloc((size_t)n * 4);
    int*   rowPtr = (int*)alloc((size_t)(n + 1) * 4);
    int*   cursor = (int*)alloc((size_t)n * 4);
    int*   blockSum = (int*)alloc(256 * 4);
    int*   edges  = (int*)alloc((size_t)E * 4);
    float* sum   = (float*)alloc(320 * 4);
    float* sumsq = (float*)alloc(320 * 4);
    float* scale = (float*)alloc(320 * 4);
    float* shift = (float*)alloc(320 * 4);

    const int total4 = n * C4;
    const int nb = (n + 1023) / 1024;    // scan blocks (98)

    // ---- one-time (per call) prep ----
    {
        convert_w_kernel<<<(5 * NP1 * Kp1 + 255) / 256, 256, 0, stream>>>(w1, w1f, 600, 300, NP1, Kp1);
        convert_w_kernel<<<(5 * NP2 * Kp2 + 255) / 256, 256, 0, stream>>>(w2, w2f, 300, 600, NP2, Kp2);
        build_ec_kernel<<<(5 * 18 * ECS + 255) / 256, 256, 0, stream>>>(e_emb1, e_emb2, ec);
        // CSR build
        hipMemsetAsync(deg, 0, (size_t)n * 4, stream);
        deg_kernel<<<(E + 255) / 256, 256, 0, stream>>>(ei, deg, E);
        scan1_kernel<<<nb, 256, 0, stream>>>(deg, cursor /*reuse as pre*/, blockSum, n);
        scan2_kernel<<<1, 256, 0, stream>>>(blockSum, nb);
        scan3_kernel<<<(n + 256) / 256, 256, 0, stream>>>(cursor, blockSum, rowPtr, deg /*reuse as cursor*/, n, E);
        fill_kernel<<<(E + 255) / 256, 256, 0, stream>>>(ei, ea, deg, edges, E);
        // agg zeroed once (tail rows stay 0); h zeroed once (layer-0 pad cols = 0)
        hipMemsetAsync(agg, 0, (size_t)MpA * Kp1 * 2, stream);
        hipMemsetAsync(h, 0, (size_t)n * HS * 2, stream);
        embed_kernel<<<(total4 + 255) / 256, 256, 0, stream>>>(x, x_emb1, x_emb2, h, total4);
    }

    const int gatherTotal = n * CG;      // 40 threads/node
    const int nCol1 = NP1 / 128;   // 5
    const int nCol2 = NP2 / 128;   // 3
    const int g1 = nRowTP * nCol1; // 7840 blocks
    const int g2 = nRowTP * nCol2; // 4704 blocks

    for (int l = 0; l < 5; l++) {
        hipMemsetAsync(sum, 0, 2 * 320 * sizeof(float), stream);  // sum+sumsq contiguous
        gather_kernel<<<(gatherTotal + 255) / 256, 256, 0, stream>>>(
            h, rowPtr, edges, ec + (size_t)l * 18 * ECS, scale, shift, l > 0 ? 1 : 0,
            agg, n);
        // GEMM1: agg[Mp,320] x w1[640,320] -> hid fp16 (relu, stride 640)
        mfma_gemm_lds<true, false><<<g1, 256, 0, stream>>>(
            agg, w1f + (size_t)l * NP1 * Kp1,
            b1 + (size_t)l * 600, hid, nullptr, nullptr,
            n, Kp1, Kp2, 600, nCol1);
        // GEMM2: hid[Mp,640] x w2[384,640] -> h fp16 (stride HS, no relu) + BN stats
        mfma_gemm_lds<false, true><<<g2, 256, 0, stream>>>(
            hid, w2f + (size_t)l * NP2 * Kp2,
            b2 + (size_t)l * 300, h, sum, sumsq,
            n, Kp2, HS, 300, nCol2);
        finalize_kernel<<<1, 320, 0, stream>>>(sum, sumsq, gamma + (size_t)l * DD,
                                               beta + (size_t)l * DD, scale, shift,
                                               1.0f / (float)n);
    }
    apply_kernel<<<(total4 + 255) / 256, 256, 0, stream>>>(h, scale, shift,
                                                           (float*)d_out, total4);
}